// Round 1
// baseline (319.929 us; speedup 1.0000x reference)
//
#include <hip/hip_runtime.h>

#define FUZZ 2187
#define NFEAT 7
#define MID 512
#define NCLS 10
#define BATCH 4096
#define SSTR 2192   // padded row stride for S/G (21 rows each)

// ---------------------------------------------------------------------------
// Kernel 1: S[jm][n] = sum over k with IDX[k,j]==m of wei[k*7+j, n]
// k = by*27 + kk. Digits j=0..3 of k come only from by (block-uniform) ->
// accumulate unconditionally into 4 regs, pick target row ONCE at the end.
// Digits j=4..6 come only from kk (compile-time under full unroll) ->
// compile-time accumulator targets. No div/mod, no cndmask in the loop.
// 13 atomics/thread (was 21). Memory-bound: streams 134 MB of wei once.
// ---------------------------------------------------------------------------
__global__ __launch_bounds__(256) void k_reduce_wei(const float* __restrict__ wei,
                                                    float* __restrict__ S) {
    int n = blockIdx.x * 256 + threadIdx.x;
    if (n >= FUZZ) return;
    int by = blockIdx.y;            // top 4 base-3 digits of k (block-uniform)
    int t = by;
    int d3 = t % 3; t /= 3;
    int d2 = t % 3; t /= 3;
    int d1 = t % 3; t /= 3;
    int d0 = t;                     // by < 81
    float accL0 = 0.f, accL1 = 0.f, accL2 = 0.f, accL3 = 0.f;
    float accH[9];
#pragma unroll
    for (int m = 0; m < 9; ++m) accH[m] = 0.f;
    const float* base = wei + (size_t)(by * 189) * FUZZ + n;
#pragma unroll
    for (int kk = 0; kk < 27; ++kk) {
        const float* rowp = base + (size_t)(kk * 7) * FUZZ;
        accL0 += rowp[0];
        accL1 += rowp[(size_t)1 * FUZZ];
        accL2 += rowp[(size_t)2 * FUZZ];
        accL3 += rowp[(size_t)3 * FUZZ];
        accH[0 + kk / 9]       += rowp[(size_t)4 * FUZZ];   // j=4 digit
        accH[3 + (kk / 3) % 3] += rowp[(size_t)5 * FUZZ];   // j=5 digit
        accH[6 + kk % 3]       += rowp[(size_t)6 * FUZZ];   // j=6 digit
    }
    atomicAdd(&S[(0 + d0) * SSTR + n], accL0);
    atomicAdd(&S[(3 + d1) * SSTR + n], accL1);
    atomicAdd(&S[(6 + d2) * SSTR + n], accL2);
    atomicAdd(&S[(9 + d3) * SSTR + n], accL3);
#pragma unroll
    for (int m = 0; m < 9; ++m)
        atomicAdd(&S[(12 + m) * SSTR + n], accH[m]);
}

__device__ __forceinline__ float wave_sum(float v) {
#pragma unroll
    for (int off = 32; off > 0; off >>= 1) v += __shfl_down(v, off, 64);
    return v;
}

// ---------------------------------------------------------------------------
// Kernel 2: SW1[jm][i] = sum_n S[jm,n]*W1[i,n];  ws1[i] = sum_n W1[i,n]
// One block (4 waves) per i; n-range split across waves, LDS reduce.
// 2048 waves (was 512) -> 4x the latency hiding.
// ---------------------------------------------------------------------------
__global__ __launch_bounds__(256) void k_sw1(const float* __restrict__ S,
                                             const float* __restrict__ W1,
                                             float* __restrict__ SW1,
                                             float* __restrict__ ws1) {
    int i = blockIdx.x;
    int tid = threadIdx.x;
    float acc[21];
    float aw = 0.f;
#pragma unroll
    for (int t = 0; t < 21; ++t) acc[t] = 0.f;
    const float* w1row = W1 + (size_t)i * FUZZ;
    for (int n = tid; n < FUZZ; n += 256) {
        float w1 = w1row[n];
        aw += w1;
#pragma unroll
        for (int t = 0; t < 21; ++t) acc[t] += S[t * SSTR + n] * w1;
    }
#pragma unroll
    for (int t = 0; t < 21; ++t) acc[t] = wave_sum(acc[t]);
    aw = wave_sum(aw);
    __shared__ float red[4][22];
    int w = tid >> 6, lane = tid & 63;
    if (lane == 0) {
#pragma unroll
        for (int t = 0; t < 21; ++t) red[w][t] = acc[t];
        red[w][21] = aw;
    }
    __syncthreads();
    if (tid < 22) {
        float s = red[0][tid] + red[1][tid] + red[2][tid] + red[3][tid];
        if (tid < 21) SW1[tid * MID + i] = s;
        else          ws1[i] = s;
    }
}

// ---------------------------------------------------------------------------
// Kernel 3: G[jm][n] = sum_i SW1[jm,i]*W2[n,i];  q[n] = sum_i ws1[i]*W2[n,i];
//           p[n] = sum_i b1[i]*W2[n,i].  One block (2 waves) per n.
// ---------------------------------------------------------------------------
__global__ __launch_bounds__(128) void k_g(const float* __restrict__ SW1,
                                           const float* __restrict__ ws1,
                                           const float* __restrict__ b1,
                                           const float* __restrict__ W2,
                                           float* __restrict__ G,
                                           float* __restrict__ q,
                                           float* __restrict__ p) {
    int n = blockIdx.x;
    int tid = threadIdx.x;
    float acc[21];
    float aq = 0.f, ap = 0.f;
#pragma unroll
    for (int t = 0; t < 21; ++t) acc[t] = 0.f;
    const float* w2row = W2 + (size_t)n * MID;
    for (int i = tid; i < MID; i += 128) {
        float w2 = w2row[i];
        aq += ws1[i] * w2;
        ap += b1[i] * w2;
#pragma unroll
        for (int t = 0; t < 21; ++t) acc[t] += SW1[t * MID + i] * w2;
    }
#pragma unroll
    for (int t = 0; t < 21; ++t) acc[t] = wave_sum(acc[t]);
    aq = wave_sum(aq);
    ap = wave_sum(ap);
    __shared__ float red[2][23];
    int w = tid >> 6, lane = tid & 63;
    if (lane == 0) {
#pragma unroll
        for (int t = 0; t < 21; ++t) red[w][t] = acc[t];
        red[w][21] = aq;
        red[w][22] = ap;
    }
    __syncthreads();
    if (tid < 23) {
        float s = red[0][tid] + red[1][tid];
        if (tid < 21)      G[tid * SSTR + n] = s;
        else if (tid == 21) q[n] = s;
        else                p[n] = s;
    }
}

// ---------------------------------------------------------------------------
// Kernel 4: H[jm][c] = sum_n (S+G)[jm,n]*W3[c,n]
//           v[c] = sum_n (1+q[n])*W3[c,n]
//           w[c] = sum_n (p[n]+b2[n])*W3[c,n] + b3[c]
//           T[jm] = sum_n S[jm,n]              (blockIdx.x == 10)
// Grid (11, 9): n-range split into 9 chunks of 243, atomicAdd epilogue.
// 99 waves (was 11). H/v/w/T must be zeroed before this kernel.
// ---------------------------------------------------------------------------
__global__ __launch_bounds__(64) void k_h(const float* __restrict__ S,
                                          const float* __restrict__ G,
                                          const float* __restrict__ q,
                                          const float* __restrict__ p,
                                          const float* __restrict__ b2,
                                          const float* __restrict__ b3,
                                          const float* __restrict__ W3,
                                          float* __restrict__ H,
                                          float* __restrict__ v,
                                          float* __restrict__ w,
                                          float* __restrict__ T) {
    int c = blockIdx.x;
    int chunk = blockIdx.y;
    int lane = threadIdx.x;
    int n0 = chunk * 243;
    if (c < NCLS) {
        float acc[21];
        float av = 0.f, aw = 0.f;
#pragma unroll
        for (int t = 0; t < 21; ++t) acc[t] = 0.f;
        for (int n = n0 + lane; n < n0 + 243; n += 64) {
            float w3 = W3[(size_t)c * FUZZ + n];
            av += (1.0f + q[n]) * w3;
            aw += (p[n] + b2[n]) * w3;
#pragma unroll
            for (int t = 0; t < 21; ++t)
                acc[t] += (S[t * SSTR + n] + G[t * SSTR + n]) * w3;
        }
#pragma unroll
        for (int t = 0; t < 21; ++t) acc[t] = wave_sum(acc[t]);
        av = wave_sum(av);
        aw = wave_sum(aw);
        if (lane == 0) {
#pragma unroll
            for (int t = 0; t < 21; ++t) atomicAdd(&H[t * NCLS + c], acc[t]);
            atomicAdd(&v[c], av);
            atomicAdd(&w[c], aw + (chunk == 0 ? b3[c] : 0.f));
        }
    } else {
        float acc[21];
#pragma unroll
        for (int t = 0; t < 21; ++t) acc[t] = 0.f;
        for (int n = n0 + lane; n < n0 + 243; n += 64) {
#pragma unroll
            for (int t = 0; t < 21; ++t) acc[t] += S[t * SSTR + n];
        }
#pragma unroll
        for (int t = 0; t < 21; ++t) acc[t] = wave_sum(acc[t]);
        if (lane == 0) {
#pragma unroll
            for (int t = 0; t < 21; ++t) atomicAdd(&T[t], acc[t]);
        }
    }
}

// ---------------------------------------------------------------------------
// Kernel 5: per-batch epilogue. 64 blocks x 64 threads spreads across CUs.
// ---------------------------------------------------------------------------
__global__ __launch_bounds__(64) void k_out(const float* __restrict__ x,
                                            const float* __restrict__ cc,
                                            const float* __restrict__ bbv,
                                            const float* __restrict__ bais,
                                            const float* __restrict__ T,
                                            const float* __restrict__ H,
                                            const float* __restrict__ v,
                                            const float* __restrict__ w,
                                            float* __restrict__ out) {
    int b = blockIdx.x * 64 + threadIdx.x;
    if (b >= BATCH) return;
    float xv[NFEAT];
#pragma unroll
    for (int j = 0; j < NFEAT; ++j) xv[j] = x[b * NFEAT + j];
    float u[21];
#pragma unroll
    for (int j = 0; j < NFEAT; ++j) {
#pragma unroll
        for (int m = 0; m < 3; ++m) {
            float d = xv[j] - cc[j * 3 + m];
            float bv = bbv[j * 3 + m];
            u[j * 3 + m] = expf(-(d * d) / (bv * bv));
        }
    }
    float ba = bais[0];
    float r = 2187.0f * ba;
#pragma unroll
    for (int t = 0; t < 21; ++t) r += u[t] * T[t];
    float inv = 1.0f / r;
#pragma unroll
    for (int c = 0; c < NCLS; ++c) {
        float s = 0.f;
#pragma unroll
        for (int t = 0; t < 21; ++t) s += u[t] * H[t * NCLS + c];
        float h = (s + ba * v[c]) * inv + w[c];
        out[b * NCLS + c] = (h >= 0.f) ? h : 0.2f * h;
    }
}

extern "C" void kernel_launch(void* const* d_in, const int* in_sizes, int n_in,
                              void* d_out, int out_size, void* d_ws, size_t ws_size,
                              hipStream_t stream) {
    const float* x    = (const float*)d_in[0];
    const float* c    = (const float*)d_in[1];
    const float* bbv  = (const float*)d_in[2];
    const float* wei  = (const float*)d_in[3];
    const float* bais = (const float*)d_in[4];
    const float* W1   = (const float*)d_in[5];
    const float* b1   = (const float*)d_in[6];
    const float* W2   = (const float*)d_in[7];
    const float* b2   = (const float*)d_in[8];
    const float* W3   = (const float*)d_in[9];
    const float* b3   = (const float*)d_in[10];

    float* ws  = (float*)d_ws;
    float* S   = ws;                         // 21*SSTR
    float* G   = S + 21 * SSTR;              // 21*SSTR
    float* SW1 = G + 21 * SSTR;              // 21*512
    float* ws1 = SW1 + 21 * MID;             // 512
    float* q   = ws1 + MID;                  // SSTR
    float* p   = q + SSTR;                   // SSTR
    float* T   = p + SSTR;                   // 32
    float* H   = T + 32;                     // 224 (21*10 used)
    float* v   = H + 224;                    // 16
    float* w   = v + 16;                     // 16

    hipMemsetAsync(S, 0, (size_t)(21 * SSTR) * sizeof(float), stream);
    hipMemsetAsync(T, 0, (size_t)288 * sizeof(float), stream);   // T,H,v,w
    k_reduce_wei<<<dim3(9, 81), 256, 0, stream>>>(wei, S);
    k_sw1<<<MID, 256, 0, stream>>>(S, W1, SW1, ws1);
    k_g<<<FUZZ, 128, 0, stream>>>(SW1, ws1, b1, W2, G, q, p);
    k_h<<<dim3(NCLS + 1, 9), 64, 0, stream>>>(S, G, q, p, b2, b3, W3, H, v, w, T);
    k_out<<<(BATCH + 63) / 64, 64, 0, stream>>>(x, c, bbv, bais, T, H, v, w,
                                                (float*)d_out);
}